// Round 1
// baseline (1022.534 us; speedup 1.0000x reference)
//
#include <hip/hip_runtime.h>
#include <hip/hip_fp16.h>

// Meta-linear: x_new[b,o] = (1/sqrt(D)) * sum_{i,k} W[o,i,k] x[b,i] x[b,k] + bias[o], twice.
// GEMM view: C[128,512] = A[128, 262144] * W^T with A[b, i*512+k] = x[b,i]*x[b,k] built on the fly.
// Memory floor: W (537 MB fp32) streamed once per depth = 1.074 GB -> ~170 us @ 6.3 TB/s.
// fp16 MFMA (16x16x32) for compute; fp32 atomic split-K accumulation.

typedef __attribute__((ext_vector_type(8))) _Float16 f16x8;
typedef __attribute__((ext_vector_type(4))) float    f32x4v;
typedef __attribute__((ext_vector_type(4))) unsigned u32x4;

#define DD 512
#define BB 128
#define INV_SQRT_D 0.04419417382415922f   // 1/sqrt(512)

static __device__ __forceinline__ unsigned pkh(float a, float b) {
    __half2 h = __float22half2_rn(make_float2(a, b));
    unsigned u;
    __builtin_memcpy(&u, &h, sizeof(u));
    return u;
}

static __device__ __forceinline__ u32x4 pack8s(f32x4v a, f32x4v b, float s) {
    u32x4 r;
    r.x = pkh(a.x * s, a.y * s);
    r.y = pkh(a.z * s, a.w * s);
    r.z = pkh(b.x * s, b.y * s);
    r.w = pkh(b.z * s, b.w * s);
    return r;
}

static __device__ __forceinline__ f16x8 as_h8(u32x4 q) {
    f16x8 v;
    __builtin_memcpy(&v, &q, sizeof(v));
    return v;
}

// Block: 64 outs (o0..o0+63, 16 per wave) x 32 i-values x 64 k-values.
// Grid: 8 o-tiles * 16 i-groups * 8 k-tiles = 1024 blocks (= 4/CU resident).
// A-tile per i (128 b x 64 k, f16) built cooperatively into LDS in
// MFMA-fragment-permuted order: entry index (ks*8 + f)*64 + lane holds the
// 8 halfs lane `lane` feeds to MFMA for m-frag f, K-step ks. Lane-sequential
// 16B entries -> conflict-free b128 LDS traffic. Double-buffered, 1 barrier/i.
__global__ __launch_bounds__(256, 4)
void metagemm(const float* __restrict__ x, const float* __restrict__ W,
              float* __restrict__ acc) {
    __shared__ u32x4 Ab[2][1024];   // 2 x 16 KB

    const int tid  = threadIdx.x;
    const int lane = tid & 63;
    const int wv   = tid >> 6;      // wave 0..3

    const int bid = blockIdx.x;
    const int ob  = bid >> 7;        // 0..7   o-tile
    const int ig  = (bid >> 3) & 15; // 0..15  i-group
    const int kp  = bid & 7;         // 0..7   k-tile

    const int o0 = ob * 64 + wv * 16;
    const int i0 = ig * 32;
    const int kb = kp * 64;

    const int l15  = lane & 15;
    const int quad = lane >> 4;
    const int koff = quad * 8;

    // builder: this thread fills entries for frags wv and wv+4 (rows bA, bB)
    const int bA = wv * 16 + l15;
    const int bB = (wv + 4) * 16 + l15;
    const float* xr0 = x + bA * DD + kb + koff;
    const float* xr1 = x + bB * DD + kb + koff;

    // consumer: W[o][i][k], this lane reads row o = o0 + l15, 8 floats at k = kb+koff (+32)
    const int oW = o0 + l15;
    const float* wbase = W + (long)oW * (DD * DD) + kb + koff;

    f32x4v c[8];
#pragma unroll
    for (int f = 0; f < 8; ++f) c[f] = (f32x4v){0.f, 0.f, 0.f, 0.f};

    auto build = [&](int buf, int i) {
        const float s0 = x[bA * DD + i] * INV_SQRT_D;
        const float s1 = x[bB * DD + i] * INV_SQRT_D;
#pragma unroll
        for (int ks = 0; ks < 2; ++ks) {
            f32x4v a0 = *(const f32x4v*)(xr0 + ks * 32);
            f32x4v a1 = *(const f32x4v*)(xr0 + ks * 32 + 4);
            f32x4v b0 = *(const f32x4v*)(xr1 + ks * 32);
            f32x4v b1 = *(const f32x4v*)(xr1 + ks * 32 + 4);
            Ab[buf][(ks * 8 + wv) * 64 + lane]     = pack8s(a0, a1, s0);
            Ab[buf][(ks * 8 + wv + 4) * 64 + lane] = pack8s(b0, b1, s1);
        }
    };

    build(0, i0);
    __syncthreads();

#pragma unroll 1
    for (int n = 0; n < 32; ++n) {
        const int i   = i0 + n;
        const int buf = n & 1;

        // issue the HBM-critical W loads first; build overlaps their latency
        const float* wp = wbase + i * DD;
        f32x4v wa = *(const f32x4v*)(wp);
        f32x4v wb = *(const f32x4v*)(wp + 4);
        f32x4v wc = *(const f32x4v*)(wp + 32);
        f32x4v wd = *(const f32x4v*)(wp + 36);

        if (n < 31) build(buf ^ 1, i + 1);

        f16x8 bf0 = as_h8(pack8s(wa, wb, 1.0f));
        f16x8 bf1 = as_h8(pack8s(wc, wd, 1.0f));

#pragma unroll
        for (int f = 0; f < 8; ++f) {
            f16x8 af = as_h8(Ab[buf][f * 64 + lane]);
            c[f] = __builtin_amdgcn_mfma_f32_16x16x32_f16(af, bf0, c[f], 0, 0, 0);
        }
#pragma unroll
        for (int f = 0; f < 8; ++f) {
            f16x8 af = as_h8(Ab[buf][(8 + f) * 64 + lane]);
            c[f] = __builtin_amdgcn_mfma_f32_16x16x32_f16(af, bf1, c[f], 0, 0, 0);
        }
        __syncthreads();
    }

    // epilogue: C/D layout col = lane&15 (o), row = quad*4 + r (b within frag)
    const int orow = o0 + l15;
    const int br0  = quad * 4;
#pragma unroll
    for (int f = 0; f < 8; ++f) {
#pragma unroll
        for (int r = 0; r < 4; ++r) {
            atomicAdd(&acc[(f * 16 + br0 + r) * DD + orow], c[f][r]);
        }
    }
}

__global__ void finalize(const float* __restrict__ acc, const float* __restrict__ bias,
                         float* __restrict__ out) {
    const int idx = blockIdx.x * 256 + threadIdx.x;
    out[idx] = acc[idx] + bias[idx & (DD - 1)];
}

extern "C" void kernel_launch(void* const* d_in, const int* in_sizes, int n_in,
                              void* d_out, int out_size, void* d_ws, size_t ws_size,
                              hipStream_t stream) {
    (void)in_sizes; (void)n_in; (void)out_size; (void)ws_size;

    const float* x    = (const float*)d_in[0];
    const float* W    = (const float*)d_in[1];
    const float* bias = (const float*)d_in[2];
    float* out = (float*)d_out;

    float* acc = (float*)d_ws;      // 65536 f32 split-K accumulator
    float* x1  = acc + BB * DD;     // 65536 f32 depth-1 output

    // depth 1
    hipMemsetAsync(acc, 0, BB * DD * sizeof(float), stream);
    metagemm<<<1024, 256, 0, stream>>>(x, W, acc);
    finalize<<<(BB * DD) / 256, 256, 0, stream>>>(acc, bias, x1);

    // depth 2 (accumulate straight into d_out, then add bias in place)
    hipMemsetAsync(out, 0, BB * DD * sizeof(float), stream);
    metagemm<<<1024, 256, 0, stream>>>(x1, W, out);
    finalize<<<(BB * DD) / 256, 256, 0, stream>>>(out, bias, out);
}

// Round 2
// 833.813 us; speedup vs baseline: 1.2263x; 1.2263x over previous
//
#include <hip/hip_runtime.h>
#include <hip/hip_fp16.h>

// Meta-linear: x_new[b,o] = (1/sqrt(D)) * sum_{i,k} W[o,i,k] x[b,i] x[b,k] + bias[o], DEPTH=2.
// GEMM view: C[128,512] = A[128, 262144] * W^T, A[b, i*512+k] = x[b,i]*x[b,k] (rank-1 per i).
// Floor: W (537 MB fp32) streamed once per depth -> ~85 us/depth @ 6.3 TB/s.
// Round-2 structure: barrier-free K-loop. A is built from two loop-invariant LDS tables
// (k-part f16, i-scalar f16-dup) via v_pk_mul_f16; W register-prefetched distance 1;
// epilogue = private partial slabs (no atomics) + reduce kernel.

typedef __attribute__((ext_vector_type(8))) _Float16 f16x8;
typedef __attribute__((ext_vector_type(4))) float    f32x4v;
typedef __attribute__((ext_vector_type(4))) unsigned u32x4;

#define DD 512
#define BB 128
#define INV_SQRT_D 0.04419417382415922f   // 1/sqrt(512)

static __device__ __forceinline__ unsigned pkh(float a, float b) {
    __half2 h = __float22half2_rn(make_float2(a, b));
    unsigned u; __builtin_memcpy(&u, &h, sizeof(u)); return u;
}
static __device__ __forceinline__ u32x4 pack8(f32x4v a, f32x4v b) {
    u32x4 r; r.x = pkh(a.x, a.y); r.y = pkh(a.z, a.w);
             r.z = pkh(b.x, b.y); r.w = pkh(b.z, b.w); return r;
}
static __device__ __forceinline__ f16x8 as_h8(u32x4 q) {
    f16x8 v; __builtin_memcpy(&v, &q, sizeof(v)); return v;
}

// Block: 64 outs (16/wave) x 32 i x 64 k. Grid: 8 o-tiles * 16 i-groups * 8 k-tiles
// = 1024 blocks = 4/CU (32 KB LDS, launch_bounds(256,4) caps VGPR at 128).
__global__ __launch_bounds__(256, 4)
void metagemm(const float* __restrict__ x, const float* __restrict__ W,
              float* __restrict__ part) {
    __shared__ u32x4    kp_lds[1024];   // 16 KB: f16 x[row, kb+..] fragments, loop-invariant
    __shared__ unsigned sc_lds[4096];   // 16 KB: dup-f16(x[row, i0+i]/sqrt(d)), [i*128+row]

    const int tid  = threadIdx.x;
    const int lane = tid & 63;
    const int wv   = tid >> 6;
    const int bid  = blockIdx.x;
    const int ob   = bid >> 7;         // o-tile 0..7
    const int ig   = (bid >> 3) & 15;  // i-group 0..15
    const int kp   = bid & 7;          // k-tile 0..7

    const int o0   = ob * 64 + wv * 16;
    const int i0   = ig * 32;
    const int kb   = kp * 64;
    const int l15  = lane & 15;
    const int quad = lane >> 4;
    const int koff = quad * 8;

    // W[o][i][k]: lane reads row o=o0+l15, 8 floats at k=kb+koff (+32)
    const float* wbase = W + (long)(o0 + l15) * (DD * DD) + (long)i0 * DD + kb + koff;

    // issue iter-0 W prefetch first — build overlaps its latency
    f32x4v wa = *(const f32x4v*)(wbase);
    f32x4v wb = *(const f32x4v*)(wbase + 4);
    f32x4v wc = *(const f32x4v*)(wbase + 32);
    f32x4v wd = *(const f32x4v*)(wbase + 36);

    // k-part table: entry (ks*8+f)*64 + lane = f16x8 of x[f*16+l15, kb+ks*32+koff .. +7]
#pragma unroll
    for (int ff = 0; ff < 2; ++ff) {
        const int f   = wv * 2 + ff;
        const int row = f * 16 + l15;
        const float* xr = x + row * DD + kb + koff;
#pragma unroll
        for (int ks = 0; ks < 2; ++ks) {
            f32x4v a = *(const f32x4v*)(xr + ks * 32);
            f32x4v b = *(const f32x4v*)(xr + ks * 32 + 4);
            kp_lds[(ks * 8 + f) * 64 + lane] = pack8(a, b);
        }
    }
    // scalar table
    {
        const int row  = tid & 127;
        const int half = tid >> 7;  // 0..1
#pragma unroll
        for (int c4 = 0; c4 < 4; ++c4) {
            const int i = half * 16 + c4 * 4;
            f32x4v v = *(const f32x4v*)(x + row * DD + i0 + i);
#pragma unroll
            for (int j = 0; j < 4; ++j) {
                float s = v[j] * INV_SQRT_D;
                sc_lds[(i + j) * 128 + row] = pkh(s, s);
            }
        }
    }
    __syncthreads();   // the only barrier

    f32x4v c[8];
#pragma unroll
    for (int f = 0; f < 8; ++f) c[f] = (f32x4v){0.f, 0.f, 0.f, 0.f};

    unsigned lic = 0;  // opaque 0: defeats LICM hoisting of loop-invariant kp_lds reads
#pragma unroll 1
    for (int n = 0; n < 32; ++n) {
        asm volatile("" : "+v"(lic));

        f32x4v ca = wa, cb = wb, cc = wc, cd = wd;
        if (n < 31) {   // distance-1 prefetch of next W row-slice
            const float* wp = wbase + (n + 1) * DD;
            wa = *(const f32x4v*)(wp);
            wb = *(const f32x4v*)(wp + 4);
            wc = *(const f32x4v*)(wp + 32);
            wd = *(const f32x4v*)(wp + 36);
        }

        f16x8 bf0 = as_h8(pack8(ca, cb));   // k = kb+koff .. +7
        f16x8 bf1 = as_h8(pack8(cc, cd));   // k = kb+32+koff .. +7

        const unsigned* scp = sc_lds + n * 128 + l15 + lic;
        const u32x4*    kpp = kp_lds + lane + lic;

#pragma unroll
        for (int f = 0; f < 8; ++f) {
            unsigned su = scp[f * 16];
            u32x4 sq = {su, su, su, su};
            f16x8 sv = as_h8(sq);
            f16x8 a0 = as_h8(kpp[f * 64]) * sv;          // 4x v_pk_mul_f16
            c[f] = __builtin_amdgcn_mfma_f32_16x16x32_f16(a0, bf0, c[f], 0, 0, 0);
            f16x8 a1 = as_h8(kpp[(8 + f) * 64]) * sv;
            c[f] = __builtin_amdgcn_mfma_f32_16x16x32_f16(a1, bf1, c[f], 0, 0, 0);
        }
    }

    // epilogue: private partial slab, plain stores (no atomics)
    // C/D layout: col = l15 (o within 16), row = quad*4 + r (b within frag)
    float* pbase = part + (long)(ig * 8 + kp) * (BB * DD) + ob * 64;
    const int ocol = wv * 16 + l15;
#pragma unroll
    for (int f = 0; f < 8; ++f) {
#pragma unroll
        for (int r = 0; r < 4; ++r) {
            pbase[(f * 16 + quad * 4 + r) * DD + ocol] = c[f][r];
        }
    }
}

__global__ void reduce_bias(const float* __restrict__ part, const float* __restrict__ bias,
                            float* __restrict__ out) {
    const int idx = blockIdx.x * 256 + threadIdx.x;
    float s = bias[idx & (DD - 1)];
#pragma unroll 16
    for (int p = 0; p < 128; ++p) s += part[(long)p * (BB * DD) + idx];
    out[idx] = s;
}

extern "C" void kernel_launch(void* const* d_in, const int* in_sizes, int n_in,
                              void* d_out, int out_size, void* d_ws, size_t ws_size,
                              hipStream_t stream) {
    (void)in_sizes; (void)n_in; (void)out_size; (void)ws_size;

    const float* x    = (const float*)d_in[0];
    const float* W    = (const float*)d_in[1];
    const float* bias = (const float*)d_in[2];
    float* out = (float*)d_out;

    float* part = (float*)d_ws;              // 128 slabs x 64 KB-elems = 32 MB
    float* x1   = part + 128 * BB * DD;      // depth-1 output

    metagemm<<<1024, 256, 0, stream>>>(x, W, part);
    reduce_bias<<<(BB * DD) / 256, 256, 0, stream>>>(part, bias, x1);

    metagemm<<<1024, 256, 0, stream>>>(x1, W, part);
    reduce_bias<<<(BB * DD) / 256, 256, 0, stream>>>(part, bias, out);
}

// Round 3
// 826.488 us; speedup vs baseline: 1.2372x; 1.0089x over previous
//
#include <hip/hip_runtime.h>
#include <hip/hip_fp16.h>

// Meta-linear: x_new[b,o] = (1/sqrt(D)) * sum_{i,k} W[o,i,k] x[b,i] x[b,k] + bias[o], DEPTH=2.
// GEMM view: C[128,512] = A[128, 262144] * W^T, A[b, i*512+k] = x[b,i]*x[b,k] (rank-1 per i).
// Floor: W (537 MB fp32) streamed once per depth -> ~85 us/depth @ 6.3 TB/s.
// Round-3: W loads are lane-CONTIGUOUS (4 rows x 256 B runs per instruction) instead of
// 16-way 1MB-strided scatter; f16 conversion in regs; wave-private XOR-swizzled 2KB LDS
// tile transposes into MFMA B-fragment layout. W register-prefetch distance 2.

typedef __attribute__((ext_vector_type(8))) _Float16 f16x8;
typedef __attribute__((ext_vector_type(4))) float    f32x4v;
typedef __attribute__((ext_vector_type(2))) unsigned u32x2;
typedef __attribute__((ext_vector_type(4))) unsigned u32x4;

#define DD 512
#define BB 128
#define INV_SQRT_D 0.04419417382415922f   // 1/sqrt(512)

static __device__ __forceinline__ unsigned pkh(float a, float b) {
    __half2 h = __float22half2_rn(make_float2(a, b));
    unsigned u; __builtin_memcpy(&u, &h, sizeof(u)); return u;
}
static __device__ __forceinline__ u32x4 pack8(f32x4v a, f32x4v b) {
    u32x4 r; r.x = pkh(a.x, a.y); r.y = pkh(a.z, a.w);
             r.z = pkh(b.x, b.y); r.w = pkh(b.z, b.w); return r;
}
static __device__ __forceinline__ f16x8 as_h8(u32x4 q) {
    f16x8 v; __builtin_memcpy(&v, &q, sizeof(v)); return v;
}

// Block: 64 outs (16/wave) x 32 i x 64 k. Grid: 8 o-tiles * 16 i-groups * 8 k-tiles
// = 1024 blocks = 4/CU (40 KB LDS, launch_bounds(256,4) caps VGPR at 128).
__global__ __launch_bounds__(256, 4)
void metagemm(const float* __restrict__ x, const float* __restrict__ W,
              float* __restrict__ part) {
    __shared__ u32x4    kp_lds[1024];    // 16 KB: f16 x[row, kb+..] A-fragments (loop-invariant)
    __shared__ unsigned sc_lds[4096];    // 16 KB: dup-f16(x[row, i0+i]/sqrt(d)), [i*128+row]
    __shared__ u32x2    wt_lds[4][256];  // 8 KB: per-wave 16 rows x 64 k f16 W tile (swizzled)

    const int tid  = threadIdx.x;
    const int lane = tid & 63;
    const int wv   = tid >> 6;
    const int bid  = blockIdx.x;
    const int ob   = bid >> 7;         // o-tile 0..7
    const int ig   = (bid >> 3) & 15;  // i-group 0..15
    const int kp   = bid & 7;          // k-tile 0..7

    const int o0   = ob * 64 + wv * 16;
    const int i0   = ig * 32;
    const int kb   = kp * 64;
    const int l15  = lane & 15;
    const int quad = lane >> 4;

    // ---- W load pattern: instr j (0..3): row r = 4j + (lane>>4), f32 16B-chunk c = lane&15
    //      -> each instruction covers 4 runs of 256 contiguous bytes (vs 16x 1MB scatter).
    const int lr = lane >> 4;   // row within group of 4
    const int lc = lane & 15;   // 16B chunk within 256B run
    const float* wp0 = W + (long)(o0 + 0 + lr) * (DD * DD) + (long)i0 * DD + kb + lc * 4;
    const float* wp1 = W + (long)(o0 + 4 + lr) * (DD * DD) + (long)i0 * DD + kb + lc * 4;
    const float* wp2 = W + (long)(o0 + 8 + lr) * (DD * DD) + (long)i0 * DD + kb + lc * 4;
    const float* wp3 = W + (long)(o0 + 12 + lr) * (DD * DD) + (long)i0 * DD + kb + lc * 4;

    // LDS W-tile addressing, XOR-swizzled on 16B chunks: logical (row, f16chunk8B/16B)
    // write (this lane, per instr j): row r = 4j+lr, f32 chunk c=lc -> f16 8 B at
    //   u32x2 index r*16 + (((c>>1) ^ (r&7))*2) + (c&1)
    u32x2* wtw0 = &wt_lds[wv][(0 + lr) * 16 + (((lc >> 1) ^ ((0 + lr) & 7)) * 2) + (lc & 1)];
    u32x2* wtw1 = &wt_lds[wv][(4 + lr) * 16 + (((lc >> 1) ^ ((4 + lr) & 7)) * 2) + (lc & 1)];
    u32x2* wtw2 = &wt_lds[wv][(8 + lr) * 16 + (((lc >> 1) ^ ((8 + lr) & 7)) * 2) + (lc & 1)];
    u32x2* wtw3 = &wt_lds[wv][(12 + lr) * 16 + (((lc >> 1) ^ ((12 + lr) & 7)) * 2) + (lc & 1)];
    // read (B-frag): kstep s, quad q: 16B chunk (s*4+q) ^ (l15&7) of row l15
    const u32x4* wtr = (const u32x4*)&wt_lds[wv][0];
    const u32x4* wtr0 = wtr + l15 * 8 + ((0 * 4 + quad) ^ (l15 & 7));
    const u32x4* wtr1 = wtr + l15 * 8 + ((1 * 4 + quad) ^ (l15 & 7));

    // ---- issue first two W prefetches (dist-2) before table build to hide latency
    f32x4v p0a = *(const f32x4v*)(wp0);
    f32x4v p0b = *(const f32x4v*)(wp1);
    f32x4v p0c = *(const f32x4v*)(wp2);
    f32x4v p0d = *(const f32x4v*)(wp3);
    f32x4v p1a = *(const f32x4v*)(wp0 + DD);
    f32x4v p1b = *(const f32x4v*)(wp1 + DD);
    f32x4v p1c = *(const f32x4v*)(wp2 + DD);
    f32x4v p1d = *(const f32x4v*)(wp3 + DD);

    // ---- k-part table: entry (ks*8+f)*64 + lane = f16x8 of x[f*16+l15, kb+ks*32+koff..+7]
    const int koff = quad * 8;
#pragma unroll
    for (int ff = 0; ff < 2; ++ff) {
        const int f   = wv * 2 + ff;
        const int row = f * 16 + l15;
        const float* xr = x + row * DD + kb + koff;
#pragma unroll
        for (int ks = 0; ks < 2; ++ks) {
            f32x4v a = *(const f32x4v*)(xr + ks * 32);
            f32x4v b = *(const f32x4v*)(xr + ks * 32 + 4);
            kp_lds[(ks * 8 + f) * 64 + lane] = pack8(a, b);
        }
    }
    // ---- scalar table
    {
        const int row  = tid & 127;
        const int half = tid >> 7;
#pragma unroll
        for (int c4 = 0; c4 < 4; ++c4) {
            const int i = half * 16 + c4 * 4;
            f32x4v v = *(const f32x4v*)(x + row * DD + i0 + i);
#pragma unroll
            for (int j = 0; j < 4; ++j) {
                float s = v[j] * INV_SQRT_D;
                sc_lds[(i + j) * 128 + row] = pkh(s, s);
            }
        }
    }
    __syncthreads();   // the only barrier

    f32x4v c[8];
#pragma unroll
    for (int f = 0; f < 8; ++f) c[f] = (f32x4v){0.f, 0.f, 0.f, 0.f};

    unsigned lic = 0;  // opaque 0: defeats LICM hoisting of loop-invariant kp_lds reads
#pragma unroll 1
    for (int n = 0; n < 32; ++n) {
        asm volatile("" : "+v"(lic));

        f32x4v ca = p0a, cb = p0b, cc = p0c, cd = p0d;
        p0a = p1a; p0b = p1b; p0c = p1c; p0d = p1d;
        if (n < 30) {   // distance-2 prefetch
            const long off = (long)(n + 2) * DD;
            p1a = *(const f32x4v*)(wp0 + off);
            p1b = *(const f32x4v*)(wp1 + off);
            p1c = *(const f32x4v*)(wp2 + off);
            p1d = *(const f32x4v*)(wp3 + off);
        }

        // stage this iter's W into the wave-private LDS tile (f16, swizzled)
        *wtw0 = (u32x2){pkh(ca.x, ca.y), pkh(ca.z, ca.w)};
        *wtw1 = (u32x2){pkh(cb.x, cb.y), pkh(cb.z, cb.w)};
        *wtw2 = (u32x2){pkh(cc.x, cc.y), pkh(cc.z, cc.w)};
        *wtw3 = (u32x2){pkh(cd.x, cd.y), pkh(cd.z, cd.w)};

        const unsigned* scp = sc_lds + n * 128 + l15 + lic;
        const u32x4*    kpp = kp_lds + lane + lic;

        // B-frags out of the swizzled tile (compiler inserts the lgkmcnt wait)
        f16x8 bf0 = as_h8(wtr0[lic]);   // k = kb + quad*8 .. +7
        f16x8 bf1 = as_h8(wtr1[lic]);   // k = kb + 32 + quad*8 .. +7

#pragma unroll
        for (int f = 0; f < 8; ++f) {
            unsigned su = scp[f * 16];
            u32x4 sq = {su, su, su, su};
            f16x8 sv = as_h8(sq);
            f16x8 a0 = as_h8(kpp[f * 64]) * sv;          // 4x v_pk_mul_f16
            c[f] = __builtin_amdgcn_mfma_f32_16x16x32_f16(a0, bf0, c[f], 0, 0, 0);
            f16x8 a1 = as_h8(kpp[(8 + f) * 64]) * sv;
            c[f] = __builtin_amdgcn_mfma_f32_16x16x32_f16(a1, bf1, c[f], 0, 0, 0);
        }
    }

    // epilogue: private partial slab, plain stores (no atomics)
    // C/D layout: col = l15 (o within 16), row = quad*4 + r (b within frag)
    float* pbase = part + (long)(ig * 8 + kp) * (BB * DD) + ob * 64;
    const int ocol = wv * 16 + l15;
#pragma unroll
    for (int f = 0; f < 8; ++f) {
#pragma unroll
        for (int r = 0; r < 4; ++r) {
            pbase[(f * 16 + quad * 4 + r) * DD + ocol] = c[f][r];
        }
    }
}

__global__ void reduce_bias(const float* __restrict__ part, const float* __restrict__ bias,
                            float* __restrict__ out) {
    const int idx = blockIdx.x * 256 + threadIdx.x;
    float s = bias[idx & (DD - 1)];
#pragma unroll 16
    for (int p = 0; p < 128; ++p) s += part[(long)p * (BB * DD) + idx];
    out[idx] = s;
}

extern "C" void kernel_launch(void* const* d_in, const int* in_sizes, int n_in,
                              void* d_out, int out_size, void* d_ws, size_t ws_size,
                              hipStream_t stream) {
    (void)in_sizes; (void)n_in; (void)out_size; (void)ws_size;

    const float* x    = (const float*)d_in[0];
    const float* W    = (const float*)d_in[1];
    const float* bias = (const float*)d_in[2];
    float* out = (float*)d_out;

    float* part = (float*)d_ws;              // 128 slabs x 64K elems = 32 MB
    float* x1   = part + 128 * BB * DD;      // depth-1 output

    metagemm<<<1024, 256, 0, stream>>>(x, W, part);
    reduce_bias<<<(BB * DD) / 256, 256, 0, stream>>>(part, bias, x1);

    metagemm<<<1024, 256, 0, stream>>>(x1, W, part);
    reduce_bias<<<(BB * DD) / 256, 256, 0, stream>>>(part, bias, out);
}